// Round 2
// baseline (618.972 us; speedup 1.0000x reference)
//
#include <hip/hip_runtime.h>
#include <math.h>

typedef unsigned short u16;
typedef unsigned int u32;
typedef __attribute__((ext_vector_type(4))) float f32x4;
typedef __attribute__((ext_vector_type(8))) unsigned short u16x8;
typedef __attribute__((ext_vector_type(4))) unsigned short u16x4;
typedef __attribute__((ext_vector_type(8))) __bf16 bf16x8;

#define DEV __device__ __forceinline__

constexpr int S = 2048;
constexpr int HIDDEN = 5120;
constexpr int H = 16;
constexpr int NOPE = 128, ROPE_D = 64, VD = 128;
constexpr int QKD = NOPE + ROPE_D;  // 192
constexpr int QLORA = 1536, KVLORA = 512;
constexpr int KVA_N = KVLORA + ROPE_D;  // 576
constexpr float SCALING = 0.11472134f;

DEV u16 f2b(float f) {
  u32 u = __builtin_bit_cast(u32, f);
  u32 r = u + 0x7FFFu + ((u >> 16) & 1u);
  return (u16)(r >> 16);
}
DEV float b2f(u16 h) { return __builtin_bit_cast(float, (u32)h << 16); }

DEV void store_out(float* p, float v) { *p = v; }
DEV void store_out(u16* p, float v) { *p = f2b(v); }

DEV void gload_lds16(const u16* g, u16* l) {
  auto* gp = (const __attribute__((address_space(1))) u16*)g;
  auto* lp = (__attribute__((address_space(3))) u16*)l;
  __builtin_amdgcn_global_load_lds(gp, lp, 16, 0, 0);
}

// XOR swizzle: spread same-column reads of consecutive rows across banks
#define SWZ(row, col) ((col) ^ (((row) & 7) << 3))

// ---------------- elementwise f32 -> bf16 ----------------
__global__ __launch_bounds__(256) void k_convert(const float* __restrict__ in,
                                                 u16* __restrict__ out, int n) {
  int i = (blockIdx.x * 256 + threadIdx.x) * 4;
  if (i >= n) return;
  f32x4 v = *reinterpret_cast<const f32x4*>(in + i);
  u16x4 o;
  o[0] = f2b(v[0]); o[1] = f2b(v[1]); o[2] = f2b(v[2]); o[3] = f2b(v[3]);
  *reinterpret_cast<u16x4*>(out + i) = o;
}

// ---------------- transpose f32[R][C] -> bf16[C][R] ----------------
__global__ __launch_bounds__(256) void k_transpose(const float* __restrict__ in,
                                                   u16* __restrict__ out, int R, int C) {
  __shared__ float t[32][33];
  int c0 = blockIdx.x * 32, r0 = blockIdx.y * 32;
  int tx = threadIdx.x, ty = threadIdx.y;
  for (int r = ty; r < 32; r += 8)
    t[r][tx] = in[(size_t)(r0 + r) * C + c0 + tx];
  __syncthreads();
  for (int r = ty; r < 32; r += 8)
    out[(size_t)(c0 + r) * R + r0 + tx] = f2b(t[tx][r]);
}

// ---------------- YaRN rope tables ----------------
__global__ __launch_bounds__(256) void k_rope_tables(float* __restrict__ cs,
                                                     float* __restrict__ sn) {
  int idx = blockIdx.x * 256 + threadIdx.x;
  if (idx >= S * 32) return;
  int s = idx >> 5, j = idx & 31;
  double pf = pow(10000.0, (double)j / 32.0);
  double inv_extra = 1.0 / pf;
  double inv_interp = 1.0 / (40.0 * pf);
  double twopi = 6.283185307179586476925286766559;
  double lnb2 = 2.0 * log(10000.0);
  double lowd = floor(64.0 * log(4096.0 / (32.0 * twopi)) / lnb2);
  if (lowd < 0.0) lowd = 0.0;
  double highd = ceil(64.0 * log(4096.0 / twopi) / lnb2);
  if (highd > 63.0) highd = 63.0;
  double denom = highd - lowd;
  if (denom < 0.001) denom = 0.001;
  double ramp = ((double)j - lowd) / denom;
  ramp = ramp < 0.0 ? 0.0 : (ramp > 1.0 ? 1.0 : ramp);
  float invf = (float)(inv_interp * ramp + inv_extra * (1.0 - ramp));
  float fr = (float)s * invf;
  cs[idx] = cosf(fr);
  sn[idx] = sinf(fr);
}

// ---------------- bf16 GEMM (m97 structure): C[M,N] = A[M,K] * BT[N,K]^T ----
// BT must be allocated (padded) to a multiple of 128 rows: unguarded DMA reads.
template <typename OutT>
__global__ __launch_bounds__(256) void k_gemm(const u16* __restrict__ A,
                                              const u16* __restrict__ BT,
                                              OutT* __restrict__ C, int M, int N, int K) {
  __shared__ u16 Al[128][32];
  __shared__ u16 Bl[128][32];
  const int tid = threadIdx.x;
  const int lane = tid & 63, wave = tid >> 6;
  const int wr = wave >> 1, wc = wave & 1;
  const int lr = lane & 15, lk = lane >> 4;
  const int mbase = blockIdx.y * 128, nbase = blockIdx.x * 128;
  // staging: wave w covers rows [32w,32w+32) via 2 DMA calls of 16 rows
  const int srow = wave * 32 + (lane >> 2);
  const int skoff = (lane & 3) * 8;
  const u16* aptr = A + (size_t)(mbase + srow) * K + skoff;
  const u16* bptr = BT + (size_t)(nbase + srow) * K + skoff;
  u16* al0 = &Al[wave * 32][0];
  u16* al1 = &Al[wave * 32 + 16][0];
  u16* bl0 = &Bl[wave * 32][0];
  u16* bl1 = &Bl[wave * 32 + 16][0];

  f32x4 acc[4][4];
#pragma unroll
  for (int mf = 0; mf < 4; ++mf)
#pragma unroll
    for (int nf = 0; nf < 4; ++nf) acc[mf][nf] = {0.f, 0.f, 0.f, 0.f};

  for (int k0 = 0; k0 < K; k0 += 32) {
    __syncthreads();  // prior iteration's LDS reads complete
    gload_lds16(aptr + k0, al0);
    gload_lds16(aptr + (size_t)16 * K + k0, al1);
    gload_lds16(bptr + k0, bl0);
    gload_lds16(bptr + (size_t)16 * K + k0, bl1);
    __syncthreads();  // compiler drains vmcnt before barrier
    bf16x8 af[4], bfr[4];
#pragma unroll
    for (int mf = 0; mf < 4; ++mf)
      af[mf] = *reinterpret_cast<const bf16x8*>(&Al[wr * 64 + mf * 16 + lr][lk * 8]);
#pragma unroll
    for (int nf = 0; nf < 4; ++nf)
      bfr[nf] = *reinterpret_cast<const bf16x8*>(&Bl[wc * 64 + nf * 16 + lr][lk * 8]);
#pragma unroll
    for (int mf = 0; mf < 4; ++mf)
#pragma unroll
      for (int nf = 0; nf < 4; ++nf)
        acc[mf][nf] = __builtin_amdgcn_mfma_f32_16x16x32_bf16(af[mf], bfr[nf], acc[mf][nf], 0, 0, 0);
  }
#pragma unroll
  for (int mf = 0; mf < 4; ++mf)
#pragma unroll
    for (int nf = 0; nf < 4; ++nf) {
      int col = nbase + wc * 64 + nf * 16 + lr;
      if (col < N) {
#pragma unroll
        for (int r = 0; r < 4; ++r) {
          int row = mbase + wr * 64 + mf * 16 + lk * 4 + r;
          store_out(&C[(size_t)row * N + col], acc[mf][nf][r]);
        }
      }
    }
}

// ---------------- RMSNorm fp32 -> bf16 ----------------
__global__ __launch_bounds__(256) void k_rmsnorm(const float* __restrict__ x,
                                                 const float* __restrict__ w,
                                                 u16* __restrict__ y, int ncols, int instride) {
  int row = blockIdx.x, tid = threadIdx.x;
  const float* xr = x + (size_t)row * instride;
  float ss = 0.f;
  for (int i = tid * 4; i < ncols; i += 1024) {
    f32x4 v = *reinterpret_cast<const f32x4*>(xr + i);
    ss += v[0] * v[0] + v[1] * v[1] + v[2] * v[2] + v[3] * v[3];
  }
  for (int off = 32; off > 0; off >>= 1) ss += __shfl_down(ss, off);
  __shared__ float red[4];
  if ((tid & 63) == 0) red[tid >> 6] = ss;
  __syncthreads();
  ss = red[0] + red[1] + red[2] + red[3];
  float sc = rsqrtf(ss / (float)ncols + 1e-6f);
  u16* yr = y + (size_t)row * ncols;
  for (int i = tid * 4; i < ncols; i += 1024) {
    f32x4 v = *reinterpret_cast<const f32x4*>(xr + i);
    u16x4 o;
    o[0] = f2b(v[0] * sc * w[i]);
    o[1] = f2b(v[1] * sc * w[i + 1]);
    o[2] = f2b(v[2] * sc * w[i + 2]);
    o[3] = f2b(v[3] * sc * w[i + 3]);
    *reinterpret_cast<u16x4*>(yr + i) = o;
  }
}

// ---------------- build qf [H][S][192], kf [H][S][192] with RoPE ----------------
__global__ __launch_bounds__(256) void k_build_qkf(const u16* __restrict__ qn,
                                                   const u16* __restrict__ kv,
                                                   const float* __restrict__ latent,
                                                   const float* __restrict__ cs,
                                                   const float* __restrict__ sn,
                                                   u16* __restrict__ qf, u16* __restrict__ kf) {
  int s = blockIdx.x, tid = threadIdx.x;
  for (int idx = tid; idx < H * NOPE; idx += 256) {
    int h = idx >> 7, dd = idx & 127;
    qf[((size_t)h * S + s) * QKD + dd] = qn[(size_t)s * (H * QKD) + h * QKD + dd];
    kf[((size_t)h * S + s) * QKD + dd] = kv[(size_t)s * (H * 256) + h * 256 + dd];
  }
  for (int idx = tid; idx < H * 32; idx += 256) {
    int h = idx >> 5, j = idx & 31;
    float c = cs[s * 32 + j], si = sn[s * 32 + j];
    float x1 = b2f(qn[(size_t)s * (H * QKD) + h * QKD + NOPE + 2 * j]);
    float x2 = b2f(qn[(size_t)s * (H * QKD) + h * QKD + NOPE + 2 * j + 1]);
    qf[((size_t)h * S + s) * QKD + NOPE + 2 * j] = f2b(x1 * c - x2 * si);
    qf[((size_t)h * S + s) * QKD + NOPE + 2 * j + 1] = f2b(x2 * c + x1 * si);
    float k1 = latent[(size_t)s * KVA_N + KVLORA + 2 * j];
    float k2 = latent[(size_t)s * KVA_N + KVLORA + 2 * j + 1];
    kf[((size_t)h * S + s) * QKD + NOPE + 2 * j] = f2b(k1 * c - k2 * si);
    kf[((size_t)h * S + s) * QKD + NOPE + 2 * j + 1] = f2b(k2 * c + k1 * si);
  }
}

// ---------------- build vt [H][128][S] (transposed V) ----------------
__global__ void k_build_vt(const u16* __restrict__ kv, u16* __restrict__ vt) {
  __shared__ u16 t[32][33];
  int s0 = blockIdx.x * 32, d0 = blockIdx.y * 32, h = blockIdx.z;
  int tx = threadIdx.x, ty = threadIdx.y;
  for (int r = ty; r < 32; r += 8)
    t[r][tx] = kv[(size_t)(s0 + r) * (H * 256) + h * 256 + NOPE + d0 + tx];
  __syncthreads();
  for (int r = ty; r < 32; r += 8)
    vt[((size_t)h * VD + d0 + r) * S + s0 + tx] = t[tx][r];
}

// ---------------- flash attention (causal), per head ----------------
// grid.x = 512 flat; blocks i and i+256 get complementary qt (work-balanced).
__global__ __launch_bounds__(256) void k_attn(const u16* __restrict__ qf,
                                              const u16* __restrict__ kf,
                                              const u16* __restrict__ vt,
                                              u16* __restrict__ attn) {
  const int bidx = blockIdx.x;
  const int j = bidx & 31;
  const int h = bidx >> 5;
  const int qt = (h < 8) ? j : 31 - j;  // pairs (j, 31-j) across the 256-block halves
  const int qbase = qt * 64;
  const int tid = threadIdx.x, wave = tid >> 6, lane = tid & 63;
  const int lr = lane & 15, lk = lane >> 4;
  __shared__ u16 Kl[64][192];
  __shared__ u16 Vl[128][64];
  __shared__ u16 Pl[4][16][64];

  bf16x8 qfrag[6];
  const u16* qrow = qf + ((size_t)h * S + qbase + wave * 16 + lr) * QKD;
#pragma unroll
  for (int d = 0; d < 6; ++d)
    qfrag[d] = *reinterpret_cast<const bf16x8*>(qrow + d * 32 + lk * 8);

  f32x4 o[8];
#pragma unroll
  for (int f = 0; f < 8; ++f) o[f] = {0.f, 0.f, 0.f, 0.f};
  float m_[4] = {-__builtin_inff(), -__builtin_inff(), -__builtin_inff(), -__builtin_inff()};
  float l_[4] = {0.f, 0.f, 0.f, 0.f};

  const int ktiles = qt + 1;
  for (int kt = 0; kt < ktiles; ++kt) {
    const int kbase = kt * 64;
    // stage K tile [64][192] (swizzled)
    for (int c = tid; c < 64 * 24; c += 256) {
      int row = c / 24, off = (c % 24) * 8;
      *reinterpret_cast<u16x8*>(&Kl[row][SWZ(row, off)]) =
          *reinterpret_cast<const u16x8*>(kf + ((size_t)h * S + kbase + row) * QKD + off);
    }
    // stage VT tile [128][64] (swizzled)
    for (int c = tid; c < 128 * 8; c += 256) {
      int row = c >> 3, off = (c & 7) * 8;
      *reinterpret_cast<u16x8*>(&Vl[row][SWZ(row, off)]) =
          *reinterpret_cast<const u16x8*>(vt + ((size_t)h * VD + row) * S + kbase + off);
    }
    __syncthreads();

    // QK^T : S[16 x 64]
    f32x4 sacc[4];
#pragma unroll
    for (int nf = 0; nf < 4; ++nf) sacc[nf] = {0.f, 0.f, 0.f, 0.f};
#pragma unroll
    for (int nf = 0; nf < 4; ++nf)
#pragma unroll
      for (int dk = 0; dk < 6; ++dk) {
        int krow = nf * 16 + lr;
        bf16x8 b = *reinterpret_cast<const bf16x8*>(&Kl[krow][SWZ(krow, dk * 32 + lk * 8)]);
        sacc[nf] = __builtin_amdgcn_mfma_f32_16x16x32_bf16(qfrag[dk], b, sacc[nf], 0, 0, 0);
      }

    // scale + causal mask + online softmax
    float sv[4][4];
    float rowmax[4] = {-__builtin_inff(), -__builtin_inff(), -__builtin_inff(), -__builtin_inff()};
#pragma unroll
    for (int nf = 0; nf < 4; ++nf) {
      int kcol = kbase + nf * 16 + lr;
#pragma unroll
      for (int r = 0; r < 4; ++r) {
        float v = sacc[nf][r] * SCALING;
        int qrow_g = qbase + wave * 16 + lk * 4 + r;
        if (kcol > qrow_g) v = -__builtin_inff();
        sv[nf][r] = v;
        rowmax[r] = fmaxf(rowmax[r], v);
      }
    }
#pragma unroll
    for (int r = 0; r < 4; ++r) {
#pragma unroll
      for (int off = 1; off < 16; off <<= 1)
        rowmax[r] = fmaxf(rowmax[r], __shfl_xor(rowmax[r], off));
    }
    float alpha[4], rowsum[4] = {0.f, 0.f, 0.f, 0.f};
#pragma unroll
    for (int r = 0; r < 4; ++r) {
      float mn = fmaxf(m_[r], rowmax[r]);
      alpha[r] = __expf(m_[r] - mn);
      m_[r] = mn;
    }
#pragma unroll
    for (int nf = 0; nf < 4; ++nf)
#pragma unroll
      for (int r = 0; r < 4; ++r) {
        float p = __expf(sv[nf][r] - m_[r]);
        sv[nf][r] = p;
        rowsum[r] += p;
      }
#pragma unroll
    for (int r = 0; r < 4; ++r) {
#pragma unroll
      for (int off = 1; off < 16; off <<= 1) rowsum[r] += __shfl_xor(rowsum[r], off);
      l_[r] = l_[r] * alpha[r] + rowsum[r];
    }
    // write P (C-layout, swizzled) to LDS, rescale O
#pragma unroll
    for (int nf = 0; nf < 4; ++nf)
#pragma unroll
      for (int r = 0; r < 4; ++r) {
        int prow = lk * 4 + r;
        Pl[wave][prow][SWZ(prow, nf * 16 + lr)] = f2b(sv[nf][r]);
      }
#pragma unroll
    for (int f = 0; f < 8; ++f)
#pragma unroll
      for (int r = 0; r < 4; ++r) o[f][r] *= alpha[r];

    // PV : O[16 x 128] += P[16 x 64] * V[64 x 128]
#pragma unroll
    for (int kk = 0; kk < 2; ++kk) {
      bf16x8 pa = *reinterpret_cast<const bf16x8*>(&Pl[wave][lr][SWZ(lr, kk * 32 + lk * 8)]);
#pragma unroll
      for (int f = 0; f < 8; ++f) {
        int vrow = f * 16 + lr;
        bf16x8 b = *reinterpret_cast<const bf16x8*>(&Vl[vrow][SWZ(vrow, kk * 32 + lk * 8)]);
        o[f] = __builtin_amdgcn_mfma_f32_16x16x32_bf16(pa, b, o[f], 0, 0, 0);
      }
    }
    __syncthreads();
  }

  // epilogue: normalize and store
#pragma unroll
  for (int f = 0; f < 8; ++f)
#pragma unroll
    for (int r = 0; r < 4; ++r) {
      int row = qbase + wave * 16 + lk * 4 + r;
      float val = o[f][r] / l_[r];
      attn[(size_t)row * (H * VD) + h * VD + f * 16 + lr] = f2b(val);
    }
}

// ---------------- host launch ----------------
extern "C" void kernel_launch(void* const* d_in, const int* in_sizes, int n_in,
                              void* d_out, int out_size, void* d_ws, size_t ws_size,
                              hipStream_t stream) {
  (void)in_sizes; (void)n_in; (void)out_size; (void)ws_size;
  const float* hidden    = (const float*)d_in[1];
  const float* w_q_a     = (const float*)d_in[2];
  const float* q_a_ln_w  = (const float*)d_in[3];
  const float* w_q_b     = (const float*)d_in[4];
  const float* w_kv_a    = (const float*)d_in[5];
  const float* kv_a_ln_w = (const float*)d_in[6];
  const float* w_kv_b    = (const float*)d_in[7];
  const float* w_o       = (const float*)d_in[8];
  float* out = (float*)d_out;

  char* ws = (char*)d_ws;
  size_t off = 0;
  auto alloc = [&](size_t bytes) {
    size_t o = off;
    off += (bytes + 255) & ~(size_t)255;
    return o;
  };
  constexpr int KVA_PAD = 640;  // 576 padded to multiple of 128 (unguarded DMA)
  size_t o_hs    = alloc((size_t)S * HIDDEN * 2);        // hs bf16; later reused as qf
  size_t o_btqa  = alloc((size_t)QLORA * HIDDEN * 2);    // later reused (with o_btkva) as bt_o
  size_t o_btkva = alloc((size_t)KVA_PAD * HIDDEN * 2);
  size_t o_btqb  = alloc((size_t)(H * QKD) * QLORA * 2);
  size_t o_btkvb = alloc((size_t)(H * 256) * KVLORA * 2);
  size_t o_qlat  = alloc((size_t)S * QLORA * 4);         // later reused as attn
  size_t o_lat   = alloc((size_t)S * KVA_N * 4);
  size_t o_qln   = alloc((size_t)S * QLORA * 2);
  size_t o_kvln  = alloc((size_t)S * KVLORA * 2);
  size_t o_qn    = alloc((size_t)S * (H * QKD) * 2);
  size_t o_kv    = alloc((size_t)S * (H * 256) * 2);
  size_t o_kf    = alloc((size_t)H * S * QKD * 2);
  size_t o_vt    = alloc((size_t)H * VD * S * 2);
  size_t o_cs    = alloc((size_t)S * 32 * 4);
  size_t o_sn    = alloc((size_t)S * 32 * 4);

  u16* hs_bf  = (u16*)(ws + o_hs);
  u16* bt_qa  = (u16*)(ws + o_btqa);
  u16* bt_kva = (u16*)(ws + o_btkva);
  u16* bt_qb  = (u16*)(ws + o_btqb);
  u16* bt_kvb = (u16*)(ws + o_btkvb);
  float* q_lat  = (float*)(ws + o_qlat);
  float* latent = (float*)(ws + o_lat);
  u16* q_ln  = (u16*)(ws + o_qln);
  u16* kv_ln = (u16*)(ws + o_kvln);
  u16* qn    = (u16*)(ws + o_qn);
  u16* kvb   = (u16*)(ws + o_kv);
  u16* kf    = (u16*)(ws + o_kf);
  u16* vt    = (u16*)(ws + o_vt);
  float* cs = (float*)(ws + o_cs);
  float* sn = (float*)(ws + o_sn);
  // aliases (lifetimes verified: source buffers dead before alias written)
  u16* qf   = (u16*)(ws + o_hs);
  u16* bt_o = (u16*)(ws + o_btqa);
  u16* attn = (u16*)(ws + o_qlat);

  dim3 t256(256), t32x8(32, 8);

  // prep
  k_convert<<<(S * HIDDEN / 4 + 255) / 256, t256, 0, stream>>>(hidden, hs_bf, S * HIDDEN);
  k_transpose<<<dim3(QLORA / 32, HIDDEN / 32), t32x8, 0, stream>>>(w_q_a, bt_qa, HIDDEN, QLORA);
  k_transpose<<<dim3(KVA_N / 32, HIDDEN / 32), t32x8, 0, stream>>>(w_kv_a, bt_kva, HIDDEN, KVA_N);
  k_transpose<<<dim3(H * QKD / 32, QLORA / 32), t32x8, 0, stream>>>(w_q_b, bt_qb, QLORA, H * QKD);
  k_transpose<<<dim3(H * 256 / 32, KVLORA / 32), t32x8, 0, stream>>>(w_kv_b, bt_kvb, KVLORA, H * 256);
  k_rope_tables<<<(S * 32 + 255) / 256, t256, 0, stream>>>(cs, sn);

  // down-projections
  k_gemm<float><<<dim3(QLORA / 128, S / 128), t256, 0, stream>>>(hs_bf, bt_qa, q_lat, S, QLORA, HIDDEN);
  k_gemm<float><<<dim3(KVA_PAD / 128, S / 128), t256, 0, stream>>>(hs_bf, bt_kva, latent, S, KVA_N, HIDDEN);

  // norms
  k_rmsnorm<<<S, t256, 0, stream>>>(q_lat, q_a_ln_w, q_ln, QLORA, QLORA);
  k_rmsnorm<<<S, t256, 0, stream>>>(latent, kv_a_ln_w, kv_ln, KVLORA, KVA_N);

  // up-projections (bf16 outputs)
  k_gemm<u16><<<dim3(H * QKD / 128, S / 128), t256, 0, stream>>>(q_ln, bt_qb, qn, S, H * QKD, QLORA);
  k_gemm<u16><<<dim3(H * 256 / 128, S / 128), t256, 0, stream>>>(kv_ln, bt_kvb, kvb, S, H * 256, KVLORA);

  // rearrange + RoPE
  k_build_qkf<<<S, t256, 0, stream>>>(qn, kvb, latent, cs, sn, qf, kf);
  k_build_vt<<<dim3(S / 32, VD / 32, H), t32x8, 0, stream>>>(kvb, vt);

  // transpose w_o (into region freed after down-projections)
  k_transpose<<<dim3(HIDDEN / 32, (H * VD) / 32), t32x8, 0, stream>>>(w_o, bt_o, H * VD, HIDDEN);

  // attention (flat 512-block grid, work-balanced qt mapping)
  k_attn<<<dim3(512), t256, 0, stream>>>(qf, kf, vt, attn);

  // output projection
  k_gemm<float><<<dim3(HIDDEN / 128, S / 128), t256, 0, stream>>>(attn, bt_o, out, S, HIDDEN, H * VD);
}

// Round 3
// 380.606 us; speedup vs baseline: 1.6263x; 1.6263x over previous
//
#include <hip/hip_runtime.h>
#include <math.h>

typedef unsigned short u16;
typedef unsigned int u32;
typedef __attribute__((ext_vector_type(4))) float f32x4;
typedef __attribute__((ext_vector_type(8))) unsigned short u16x8;
typedef __attribute__((ext_vector_type(4))) unsigned short u16x4;
typedef __attribute__((ext_vector_type(8))) __bf16 bf16x8;

#define DEV __device__ __forceinline__

constexpr int S = 2048;
constexpr int HIDDEN = 5120;
constexpr int H = 16;
constexpr int NOPE = 128, ROPE_D = 64, VD = 128;
constexpr int QKD = NOPE + ROPE_D;  // 192
constexpr int QLORA = 1536, KVLORA = 512;
constexpr int KVA_N = KVLORA + ROPE_D;  // 576
constexpr float SCALING = 0.11472134f;

DEV u16 f2b(float f) {
  u32 u = __builtin_bit_cast(u32, f);
  u32 r = u + 0x7FFFu + ((u >> 16) & 1u);
  return (u16)(r >> 16);
}
DEV float b2f(u16 h) { return __builtin_bit_cast(float, (u32)h << 16); }

DEV void store_out(float* p, float v) { *p = v; }
DEV void store_out(u16* p, float v) { *p = f2b(v); }

DEV void gload_lds16(const u16* g, u16* l) {
  auto* gp = (const __attribute__((address_space(1))) u16*)g;
  auto* lp = (__attribute__((address_space(3))) u16*)l;
  __builtin_amdgcn_global_load_lds(gp, lp, 16, 0, 0);
}

#define SWZ(row, col) ((col) ^ (((row) & 7) << 3))

// ---------------- elementwise f32 -> bf16 ----------------
__global__ __launch_bounds__(256) void k_convert(const float* __restrict__ in,
                                                 u16* __restrict__ out, int n) {
  int i = (blockIdx.x * 256 + threadIdx.x) * 4;
  if (i >= n) return;
  f32x4 v = *reinterpret_cast<const f32x4*>(in + i);
  u16x4 o;
  o[0] = f2b(v[0]); o[1] = f2b(v[1]); o[2] = f2b(v[2]); o[3] = f2b(v[3]);
  *reinterpret_cast<u16x4*>(out + i) = o;
}

// ---------------- transpose f32[R][C] -> bf16[C][R] ----------------
__global__ __launch_bounds__(256) void k_transpose(const float* __restrict__ in,
                                                   u16* __restrict__ out, int R, int C) {
  __shared__ float t[32][33];
  int c0 = blockIdx.x * 32, r0 = blockIdx.y * 32;
  int tx = threadIdx.x, ty = threadIdx.y;
  for (int r = ty; r < 32; r += 8)
    t[r][tx] = in[(size_t)(r0 + r) * C + c0 + tx];
  __syncthreads();
  for (int r = ty; r < 32; r += 8)
    out[(size_t)(c0 + r) * R + r0 + tx] = f2b(t[tx][r]);
}

// ---------------- YaRN rope tables ----------------
__global__ __launch_bounds__(256) void k_rope_tables(float* __restrict__ cs,
                                                     float* __restrict__ sn) {
  int idx = blockIdx.x * 256 + threadIdx.x;
  if (idx >= S * 32) return;
  int s = idx >> 5, j = idx & 31;
  double pf = pow(10000.0, (double)j / 32.0);
  double inv_extra = 1.0 / pf;
  double inv_interp = 1.0 / (40.0 * pf);
  double twopi = 6.283185307179586476925286766559;
  double lnb2 = 2.0 * log(10000.0);
  double lowd = floor(64.0 * log(4096.0 / (32.0 * twopi)) / lnb2);
  if (lowd < 0.0) lowd = 0.0;
  double highd = ceil(64.0 * log(4096.0 / twopi) / lnb2);
  if (highd > 63.0) highd = 63.0;
  double denom = highd - lowd;
  if (denom < 0.001) denom = 0.001;
  double ramp = ((double)j - lowd) / denom;
  ramp = ramp < 0.0 ? 0.0 : (ramp > 1.0 ? 1.0 : ramp);
  float invf = (float)(inv_interp * ramp + inv_extra * (1.0 - ramp));
  float fr = (float)s * invf;
  cs[idx] = cosf(fr);
  sn[idx] = sinf(fr);
}

// ---------------- bf16 GEMM body: dbuf LDS + counted vmcnt ----------------
// C[2048,N] = A[2048,K] * BT[N,K]^T.  BT rows padded to multiple of 128.
template <typename OutT>
DEV void gemm_body(u16* Al, u16* Bl, const u16* __restrict__ A,
                   const u16* __restrict__ BT, OutT* __restrict__ C,
                   int N, int K, int mbase, int nbase) {
  const int tid = threadIdx.x;
  const int lane = tid & 63, wave = tid >> 6;
  const int wr = wave >> 1, wc = wave & 1;
  const int lr = lane & 15, lk = lane >> 4;
  const int srow = wave * 32 + (lane >> 2);
  const int skoff = (lane & 3) * 8;
  const u16* aptr = A + (size_t)(mbase + srow) * K + skoff;
  const u16* bptr = BT + (size_t)(nbase + srow) * K + skoff;
  u16* alw = Al + wave * (32 * 32);  // wave-uniform LDS base, lane*16B implicit
  u16* blw = Bl + wave * (32 * 32);

  auto STAGE = [&](int b, int kk) {
    gload_lds16(aptr + kk, alw + b * 4096);
    gload_lds16(aptr + (size_t)16 * K + kk, alw + b * 4096 + 16 * 32);
    gload_lds16(bptr + kk, blw + b * 4096);
    gload_lds16(bptr + (size_t)16 * K + kk, blw + b * 4096 + 16 * 32);
  };

  f32x4 acc[4][4];
#pragma unroll
  for (int mf = 0; mf < 4; ++mf)
#pragma unroll
    for (int nf = 0; nf < 4; ++nf) acc[mf][nf] = {0.f, 0.f, 0.f, 0.f};

  const int nt = K >> 5;
  STAGE(0, 0);
  STAGE(1, 32);
  for (int t = 0; t < nt; ++t) {
    const int cur = t & 1;
    if (t + 1 < nt)
      asm volatile("s_waitcnt vmcnt(4)" ::: "memory");  // cur tile done, next in flight
    else
      asm volatile("s_waitcnt vmcnt(0)" ::: "memory");
    __builtin_amdgcn_s_barrier();
    const u16* Ac = Al + cur * 4096;
    const u16* Bc = Bl + cur * 4096;
    bf16x8 af[4], bfr[4];
#pragma unroll
    for (int mf = 0; mf < 4; ++mf)
      af[mf] = *reinterpret_cast<const bf16x8*>(Ac + (wr * 64 + mf * 16 + lr) * 32 + lk * 8);
#pragma unroll
    for (int nf = 0; nf < 4; ++nf)
      bfr[nf] = *reinterpret_cast<const bf16x8*>(Bc + (wc * 64 + nf * 16 + lr) * 32 + lk * 8);
#pragma unroll
    for (int mf = 0; mf < 4; ++mf)
#pragma unroll
      for (int nf = 0; nf < 4; ++nf)
        acc[mf][nf] = __builtin_amdgcn_mfma_f32_16x16x32_bf16(af[mf], bfr[nf], acc[mf][nf], 0, 0, 0);
    __builtin_amdgcn_s_barrier();  // everyone done reading buf[cur]
    if (t + 2 < nt) STAGE(cur, (t + 2) * 32);
  }

#pragma unroll
  for (int mf = 0; mf < 4; ++mf)
#pragma unroll
    for (int nf = 0; nf < 4; ++nf) {
      int col = nbase + wc * 64 + nf * 16 + lr;
      if (col < N) {
#pragma unroll
        for (int r = 0; r < 4; ++r) {
          int row = mbase + wr * 64 + mf * 16 + lk * 4 + r;
          store_out(&C[(size_t)row * N + col], acc[mf][nf][r]);
        }
      }
    }
}

template <typename OutT>
__global__ __launch_bounds__(256) void k_gemm(const u16* __restrict__ A,
                                              const u16* __restrict__ BT,
                                              OutT* __restrict__ C, int N, int K) {
  __shared__ u16 Al[2 * 128 * 32];
  __shared__ u16 Bl[2 * 128 * 32];
  gemm_body(Al, Bl, A, BT, C, N, K, blockIdx.y * 128, blockIdx.x * 128);
}

// two independent GEMMs in one launch (fills the machine)
template <typename OutT>
__global__ __launch_bounds__(256) void k_gemm2(const u16* __restrict__ A0, const u16* __restrict__ B0,
                                               OutT* __restrict__ C0, int N0, int K0, int nbx0,
                                               const u16* __restrict__ A1, const u16* __restrict__ B1,
                                               OutT* __restrict__ C1, int N1, int K1) {
  __shared__ u16 Al[2 * 128 * 32];
  __shared__ u16 Bl[2 * 128 * 32];
  int bx = blockIdx.x;
  if (bx < nbx0)
    gemm_body(Al, Bl, A0, B0, C0, N0, K0, blockIdx.y * 128, bx * 128);
  else
    gemm_body(Al, Bl, A1, B1, C1, N1, K1, blockIdx.y * 128, (bx - nbx0) * 128);
}

// ---------------- RMSNorm fp32 -> bf16 ----------------
__global__ __launch_bounds__(256) void k_rmsnorm(const float* __restrict__ x,
                                                 const float* __restrict__ w,
                                                 u16* __restrict__ y, int ncols, int instride) {
  int row = blockIdx.x, tid = threadIdx.x;
  const float* xr = x + (size_t)row * instride;
  float ss = 0.f;
  for (int i = tid * 4; i < ncols; i += 1024) {
    f32x4 v = *reinterpret_cast<const f32x4*>(xr + i);
    ss += v[0] * v[0] + v[1] * v[1] + v[2] * v[2] + v[3] * v[3];
  }
  for (int off = 32; off > 0; off >>= 1) ss += __shfl_down(ss, off);
  __shared__ float red[4];
  if ((tid & 63) == 0) red[tid >> 6] = ss;
  __syncthreads();
  ss = red[0] + red[1] + red[2] + red[3];
  float sc = rsqrtf(ss / (float)ncols + 1e-6f);
  u16* yr = y + (size_t)row * ncols;
  for (int i = tid * 4; i < ncols; i += 1024) {
    f32x4 v = *reinterpret_cast<const f32x4*>(xr + i);
    u16x4 o;
    o[0] = f2b(v[0] * sc * w[i]);
    o[1] = f2b(v[1] * sc * w[i + 1]);
    o[2] = f2b(v[2] * sc * w[i + 2]);
    o[3] = f2b(v[3] * sc * w[i + 3]);
    *reinterpret_cast<u16x4*>(yr + i) = o;
  }
}

// ---------------- build qf [H][S][192], kf [H][S][192] with RoPE ----------------
__global__ __launch_bounds__(256) void k_build_qkf(const u16* __restrict__ qn,
                                                   const u16* __restrict__ kv,
                                                   const float* __restrict__ latent,
                                                   const float* __restrict__ cs,
                                                   const float* __restrict__ sn,
                                                   u16* __restrict__ qf, u16* __restrict__ kf) {
  int s = blockIdx.x, tid = threadIdx.x;
  for (int idx = tid; idx < H * NOPE; idx += 256) {
    int h = idx >> 7, dd = idx & 127;
    qf[((size_t)h * S + s) * QKD + dd] = qn[(size_t)s * (H * QKD) + h * QKD + dd];
    kf[((size_t)h * S + s) * QKD + dd] = kv[(size_t)s * (H * 256) + h * 256 + dd];
  }
  for (int idx = tid; idx < H * 32; idx += 256) {
    int h = idx >> 5, j = idx & 31;
    float c = cs[s * 32 + j], si = sn[s * 32 + j];
    float x1 = b2f(qn[(size_t)s * (H * QKD) + h * QKD + NOPE + 2 * j]);
    float x2 = b2f(qn[(size_t)s * (H * QKD) + h * QKD + NOPE + 2 * j + 1]);
    qf[((size_t)h * S + s) * QKD + NOPE + 2 * j] = f2b(x1 * c - x2 * si);
    qf[((size_t)h * S + s) * QKD + NOPE + 2 * j + 1] = f2b(x2 * c + x1 * si);
    float k1 = latent[(size_t)s * KVA_N + KVLORA + 2 * j];
    float k2 = latent[(size_t)s * KVA_N + KVLORA + 2 * j + 1];
    kf[((size_t)h * S + s) * QKD + NOPE + 2 * j] = f2b(k1 * c - k2 * si);
    kf[((size_t)h * S + s) * QKD + NOPE + 2 * j + 1] = f2b(k2 * c + k1 * si);
  }
}

// ---------------- build vt [H][128][S] (transposed V) ----------------
__global__ void k_build_vt(const u16* __restrict__ kv, u16* __restrict__ vt) {
  __shared__ u16 t[32][33];
  int s0 = blockIdx.x * 32, d0 = blockIdx.y * 32, h = blockIdx.z;
  int tx = threadIdx.x, ty = threadIdx.y;
  for (int r = ty; r < 32; r += 8)
    t[r][tx] = kv[(size_t)(s0 + r) * (H * 256) + h * 256 + NOPE + d0 + tx];
  __syncthreads();
  for (int r = ty; r < 32; r += 8)
    vt[((size_t)h * VD + d0 + r) * S + s0 + tx] = t[tx][r];
}

// ---------------- flash attention (causal), per head ----------------
// T14 async-STAGE: next tile loaded to regs before compute; raw barriers keep
// global loads in flight across the sync.
__global__ __launch_bounds__(256) void k_attn(const u16* __restrict__ qf,
                                              const u16* __restrict__ kf,
                                              const u16* __restrict__ vt,
                                              u16* __restrict__ attn) {
  const int bidx = blockIdx.x;
  const int j = bidx & 31;
  const int h = bidx >> 5;
  const int qt = (h < 8) ? j : 31 - j;
  const int qbase = qt * 64;
  const int tid = threadIdx.x, wave = tid >> 6, lane = tid & 63;
  const int lr = lane & 15, lk = lane >> 4;
  __shared__ u16 Kl[64][192];
  __shared__ u16 Vl[128][64];
  __shared__ u16 Pl[4][16][64];

  // staging index precompute (static per thread)
  int krow_[6], kofs_[6], vrow_[4], vofs_[4];
#pragma unroll
  for (int i = 0; i < 6; ++i) { int c = tid + i * 256; krow_[i] = c / 24; kofs_[i] = (c % 24) * 8; }
#pragma unroll
  for (int i = 0; i < 4; ++i) { int c = tid + i * 256; vrow_[i] = c >> 3; vofs_[i] = (c & 7) * 8; }
  const u16* kfh = kf + (size_t)h * S * QKD;
  const u16* vth = vt + (size_t)h * VD * S;

  bf16x8 qfrag[6];
  const u16* qrow = qf + ((size_t)h * S + qbase + wave * 16 + lr) * QKD;
#pragma unroll
  for (int d = 0; d < 6; ++d)
    qfrag[d] = *reinterpret_cast<const bf16x8*>(qrow + d * 32 + lk * 8);

  // prologue: tile 0 into regs
  u16x8 kreg[6], vreg[4];
#pragma unroll
  for (int i = 0; i < 6; ++i)
    kreg[i] = *reinterpret_cast<const u16x8*>(kfh + (size_t)krow_[i] * QKD + kofs_[i]);
#pragma unroll
  for (int i = 0; i < 4; ++i)
    vreg[i] = *reinterpret_cast<const u16x8*>(vth + (size_t)vrow_[i] * S + vofs_[i]);

  f32x4 o[8];
#pragma unroll
  for (int f = 0; f < 8; ++f) o[f] = {0.f, 0.f, 0.f, 0.f};
  float m_[4] = {-__builtin_inff(), -__builtin_inff(), -__builtin_inff(), -__builtin_inff()};
  float l_[4] = {0.f, 0.f, 0.f, 0.f};

  const int ktiles = qt + 1;
  for (int kt = 0; kt < ktiles; ++kt) {
    const int kbase = kt * 64;
    __builtin_amdgcn_s_barrier();  // all waves done reading LDS (prev tile)
#pragma unroll
    for (int i = 0; i < 6; ++i)
      *reinterpret_cast<u16x8*>(&Kl[krow_[i]][SWZ(krow_[i], kofs_[i])]) = kreg[i];
#pragma unroll
    for (int i = 0; i < 4; ++i)
      *reinterpret_cast<u16x8*>(&Vl[vrow_[i]][SWZ(vrow_[i], vofs_[i])]) = vreg[i];
    if (kt + 1 < ktiles) {
      const int nb = kbase + 64;
#pragma unroll
      for (int i = 0; i < 6; ++i)
        kreg[i] = *reinterpret_cast<const u16x8*>(kfh + (size_t)(nb + krow_[i]) * QKD + kofs_[i]);
#pragma unroll
      for (int i = 0; i < 4; ++i)
        vreg[i] = *reinterpret_cast<const u16x8*>(vth + (size_t)vrow_[i] * S + nb + vofs_[i]);
    }
    asm volatile("s_waitcnt lgkmcnt(0)" ::: "memory");  // ds_writes done (vm stays in flight)
    __builtin_amdgcn_s_barrier();

    // QK^T : S[16 x 64]
    f32x4 sacc[4];
#pragma unroll
    for (int nf = 0; nf < 4; ++nf) sacc[nf] = {0.f, 0.f, 0.f, 0.f};
    __builtin_amdgcn_s_setprio(1);
#pragma unroll
    for (int nf = 0; nf < 4; ++nf)
#pragma unroll
      for (int dk = 0; dk < 6; ++dk) {
        int krow = nf * 16 + lr;
        bf16x8 b = *reinterpret_cast<const bf16x8*>(&Kl[krow][SWZ(krow, dk * 32 + lk * 8)]);
        sacc[nf] = __builtin_amdgcn_mfma_f32_16x16x32_bf16(qfrag[dk], b, sacc[nf], 0, 0, 0);
      }
    __builtin_amdgcn_s_setprio(0);

    // scale + causal mask + online softmax
    float sv[4][4];
    float rowmax[4] = {-__builtin_inff(), -__builtin_inff(), -__builtin_inff(), -__builtin_inff()};
#pragma unroll
    for (int nf = 0; nf < 4; ++nf) {
      int kcol = kbase + nf * 16 + lr;
#pragma unroll
      for (int r = 0; r < 4; ++r) {
        float v = sacc[nf][r] * SCALING;
        int qrow_g = qbase + wave * 16 + lk * 4 + r;
        if (kcol > qrow_g) v = -__builtin_inff();
        sv[nf][r] = v;
        rowmax[r] = fmaxf(rowmax[r], v);
      }
    }
#pragma unroll
    for (int r = 0; r < 4; ++r) {
#pragma unroll
      for (int off = 1; off < 16; off <<= 1)
        rowmax[r] = fmaxf(rowmax[r], __shfl_xor(rowmax[r], off));
    }
    float alpha[4], rowsum[4] = {0.f, 0.f, 0.f, 0.f};
#pragma unroll
    for (int r = 0; r < 4; ++r) {
      float mn = fmaxf(m_[r], rowmax[r]);
      alpha[r] = __expf(m_[r] - mn);
      m_[r] = mn;
    }
#pragma unroll
    for (int nf = 0; nf < 4; ++nf)
#pragma unroll
      for (int r = 0; r < 4; ++r) {
        float p = __expf(sv[nf][r] - m_[r]);
        sv[nf][r] = p;
        rowsum[r] += p;
      }
#pragma unroll
    for (int r = 0; r < 4; ++r) {
#pragma unroll
      for (int off = 1; off < 16; off <<= 1) rowsum[r] += __shfl_xor(rowsum[r], off);
      l_[r] = l_[r] * alpha[r] + rowsum[r];
    }
#pragma unroll
    for (int nf = 0; nf < 4; ++nf)
#pragma unroll
      for (int r = 0; r < 4; ++r) {
        int prow = lk * 4 + r;
        Pl[wave][prow][SWZ(prow, nf * 16 + lr)] = f2b(sv[nf][r]);
      }
#pragma unroll
    for (int f = 0; f < 8; ++f)
#pragma unroll
      for (int r = 0; r < 4; ++r) o[f][r] *= alpha[r];

    // PV : O[16 x 128] += P[16 x 64] * V[64 x 128]
    __builtin_amdgcn_s_setprio(1);
#pragma unroll
    for (int kk = 0; kk < 2; ++kk) {
      bf16x8 pa = *reinterpret_cast<const bf16x8*>(&Pl[wave][lr][SWZ(lr, kk * 32 + lk * 8)]);
#pragma unroll
      for (int f = 0; f < 8; ++f) {
        int vrow = f * 16 + lr;
        bf16x8 b = *reinterpret_cast<const bf16x8*>(&Vl[vrow][SWZ(vrow, kk * 32 + lk * 8)]);
        o[f] = __builtin_amdgcn_mfma_f32_16x16x32_bf16(pa, b, o[f], 0, 0, 0);
      }
    }
    __builtin_amdgcn_s_setprio(0);
  }

  // epilogue: normalize and store
#pragma unroll
  for (int f = 0; f < 8; ++f)
#pragma unroll
    for (int r = 0; r < 4; ++r) {
      int row = qbase + wave * 16 + lk * 4 + r;
      float val = o[f][r] / l_[r];
      attn[(size_t)row * (H * VD) + h * VD + f * 16 + lr] = f2b(val);
    }
}

// ---------------- host launch ----------------
extern "C" void kernel_launch(void* const* d_in, const int* in_sizes, int n_in,
                              void* d_out, int out_size, void* d_ws, size_t ws_size,
                              hipStream_t stream) {
  (void)in_sizes; (void)n_in; (void)out_size; (void)ws_size;
  const float* hidden    = (const float*)d_in[1];
  const float* w_q_a     = (const float*)d_in[2];
  const float* q_a_ln_w  = (const float*)d_in[3];
  const float* w_q_b     = (const float*)d_in[4];
  const float* w_kv_a    = (const float*)d_in[5];
  const float* kv_a_ln_w = (const float*)d_in[6];
  const float* w_kv_b    = (const float*)d_in[7];
  const float* w_o       = (const float*)d_in[8];
  float* out = (float*)d_out;

  char* ws = (char*)d_ws;
  size_t off = 0;
  auto alloc = [&](size_t bytes) {
    size_t o = off;
    off += (bytes + 255) & ~(size_t)255;
    return o;
  };
  constexpr int KVA_PAD = 640;  // 576 padded to multiple of 128 (unguarded DMA)
  size_t o_hs    = alloc((size_t)S * HIDDEN * 2);        // hs bf16; later reused as qf
  size_t o_btqa  = alloc((size_t)QLORA * HIDDEN * 2);    // later reused (with o_btkva) as bt_o
  size_t o_btkva = alloc((size_t)KVA_PAD * HIDDEN * 2);
  size_t o_btqb  = alloc((size_t)(H * QKD) * QLORA * 2);
  size_t o_btkvb = alloc((size_t)(H * 256) * KVLORA * 2);
  size_t o_qlat  = alloc((size_t)S * QLORA * 4);         // later reused as attn
  size_t o_lat   = alloc((size_t)S * KVA_N * 4);
  size_t o_qln   = alloc((size_t)S * QLORA * 2);
  size_t o_kvln  = alloc((size_t)S * KVLORA * 2);
  size_t o_qn    = alloc((size_t)S * (H * QKD) * 2);
  size_t o_kv    = alloc((size_t)S * (H * 256) * 2);
  size_t o_kf    = alloc((size_t)H * S * QKD * 2);
  size_t o_vt    = alloc((size_t)H * VD * S * 2);
  size_t o_cs    = alloc((size_t)S * 32 * 4);
  size_t o_sn    = alloc((size_t)S * 32 * 4);

  u16* hs_bf  = (u16*)(ws + o_hs);
  u16* bt_qa  = (u16*)(ws + o_btqa);
  u16* bt_kva = (u16*)(ws + o_btkva);
  u16* bt_qb  = (u16*)(ws + o_btqb);
  u16* bt_kvb = (u16*)(ws + o_btkvb);
  float* q_lat  = (float*)(ws + o_qlat);
  float* latent = (float*)(ws + o_lat);
  u16* q_ln  = (u16*)(ws + o_qln);
  u16* kv_ln = (u16*)(ws + o_kvln);
  u16* qn    = (u16*)(ws + o_qn);
  u16* kvb   = (u16*)(ws + o_kv);
  u16* kf    = (u16*)(ws + o_kf);
  u16* vt    = (u16*)(ws + o_vt);
  float* cs = (float*)(ws + o_cs);
  float* sn = (float*)(ws + o_sn);
  // aliases (lifetimes verified: source buffers dead before alias written)
  u16* qf   = (u16*)(ws + o_hs);
  u16* bt_o = (u16*)(ws + o_btqa);
  u16* attn = (u16*)(ws + o_qlat);

  dim3 t256(256), t32x8(32, 8);

  // prep
  k_convert<<<(S * HIDDEN / 4 + 255) / 256, t256, 0, stream>>>(hidden, hs_bf, S * HIDDEN);
  k_transpose<<<dim3(QLORA / 32, HIDDEN / 32), t32x8, 0, stream>>>(w_q_a, bt_qa, HIDDEN, QLORA);
  k_transpose<<<dim3(KVA_N / 32, HIDDEN / 32), t32x8, 0, stream>>>(w_kv_a, bt_kva, HIDDEN, KVA_N);
  k_transpose<<<dim3(H * QKD / 32, QLORA / 32), t32x8, 0, stream>>>(w_q_b, bt_qb, QLORA, H * QKD);
  k_transpose<<<dim3(H * 256 / 32, KVLORA / 32), t32x8, 0, stream>>>(w_kv_b, bt_kvb, KVLORA, H * 256);
  k_rope_tables<<<(S * 32 + 255) / 256, t256, 0, stream>>>(cs, sn);

  // down-projections: G1 (N=1536) + G2 (N=640pad/576) grouped, 272 blocks
  k_gemm2<float><<<dim3(QLORA / 128 + KVA_PAD / 128, S / 128), t256, 0, stream>>>(
      hs_bf, bt_qa, q_lat, QLORA, HIDDEN, QLORA / 128,
      hs_bf, bt_kva, latent, KVA_N, HIDDEN);

  // norms
  k_rmsnorm<<<S, t256, 0, stream>>>(q_lat, q_a_ln_w, q_ln, QLORA, QLORA);
  k_rmsnorm<<<S, t256, 0, stream>>>(latent, kv_a_ln_w, kv_ln, KVLORA, KVA_N);

  // up-projections: G3 (N=3072,K=1536) + G4 (N=4096,K=512) grouped, 896 blocks
  k_gemm2<u16><<<dim3((H * QKD) / 128 + (H * 256) / 128, S / 128), t256, 0, stream>>>(
      q_ln, bt_qb, qn, H * QKD, QLORA, (H * QKD) / 128,
      kv_ln, bt_kvb, kvb, H * 256, KVLORA);

  // rearrange + RoPE
  k_build_qkf<<<S, t256, 0, stream>>>(qn, kvb, latent, cs, sn, qf, kf);
  k_build_vt<<<dim3(S / 32, VD / 32, H), t32x8, 0, stream>>>(kvb, vt);

  // transpose w_o (into region freed after down-projections)
  k_transpose<<<dim3(HIDDEN / 32, (H * VD) / 32), t32x8, 0, stream>>>(w_o, bt_o, H * VD, HIDDEN);

  // attention (flat 512-block grid, work-balanced qt mapping)
  k_attn<<<dim3(512), t256, 0, stream>>>(qf, kf, vt, attn);

  // output projection
  k_gemm<float><<<dim3(HIDDEN / 128, S / 128), t256, 0, stream>>>(attn, bt_o, out, S * 0 + HIDDEN, H * VD);
}

// Round 4
// 378.281 us; speedup vs baseline: 1.6363x; 1.0061x over previous
//
#include <hip/hip_runtime.h>
#include <math.h>

typedef unsigned short u16;
typedef unsigned int u32;
typedef __attribute__((ext_vector_type(4))) float f32x4;
typedef __attribute__((ext_vector_type(8))) unsigned short u16x8;
typedef __attribute__((ext_vector_type(4))) unsigned short u16x4;
typedef __attribute__((ext_vector_type(8))) __bf16 bf16x8;

#define DEV __device__ __forceinline__

constexpr int S = 2048;
constexpr int HIDDEN = 5120;
constexpr int H = 16;
constexpr int NOPE = 128, ROPE_D = 64, VD = 128;
constexpr int QKD = NOPE + ROPE_D;  // 192
constexpr int QLORA = 1536, KVLORA = 512;
constexpr int KVA_N = KVLORA + ROPE_D;  // 576
constexpr float SCALING = 0.11472134f;

DEV u16 f2b(float f) {
  u32 u = __builtin_bit_cast(u32, f);
  u32 r = u + 0x7FFFu + ((u >> 16) & 1u);
  return (u16)(r >> 16);
}
DEV float b2f(u16 h) { return __builtin_bit_cast(float, (u32)h << 16); }

DEV void store_out(float* p, float v) { *p = v; }
DEV void store_out(u16* p, float v) { *p = f2b(v); }

DEV void gload_lds16(const u16* g, u16* l) {
  auto* gp = (const __attribute__((address_space(1))) u16*)g;
  auto* lp = (__attribute__((address_space(3))) u16*)l;
  __builtin_amdgcn_global_load_lds(gp, lp, 16, 0, 0);
}

#define SWZ(row, col) ((col) ^ (((row) & 7) << 3))

// ---------------- elementwise f32 -> bf16 ----------------
__global__ __launch_bounds__(256) void k_convert(const float* __restrict__ in,
                                                 u16* __restrict__ out, int n) {
  int i = (blockIdx.x * 256 + threadIdx.x) * 4;
  if (i >= n) return;
  f32x4 v = *reinterpret_cast<const f32x4*>(in + i);
  u16x4 o;
  o[0] = f2b(v[0]); o[1] = f2b(v[1]); o[2] = f2b(v[2]); o[3] = f2b(v[3]);
  *reinterpret_cast<u16x4*>(out + i) = o;
}

// ---------------- transpose f32[R][C] -> bf16[C][R] ----------------
__global__ __launch_bounds__(256) void k_transpose(const float* __restrict__ in,
                                                   u16* __restrict__ out, int R, int C) {
  __shared__ float t[32][33];
  int c0 = blockIdx.x * 32, r0 = blockIdx.y * 32;
  int tx = threadIdx.x, ty = threadIdx.y;
  for (int r = ty; r < 32; r += 8)
    t[r][tx] = in[(size_t)(r0 + r) * C + c0 + tx];
  __syncthreads();
  for (int r = ty; r < 32; r += 8)
    out[(size_t)(c0 + r) * R + r0 + tx] = f2b(t[tx][r]);
}

// ---------------- YaRN rope tables ----------------
__global__ __launch_bounds__(256) void k_rope_tables(float* __restrict__ cs,
                                                     float* __restrict__ sn) {
  int idx = blockIdx.x * 256 + threadIdx.x;
  if (idx >= S * 32) return;
  int s = idx >> 5, j = idx & 31;
  double pf = pow(10000.0, (double)j / 32.0);
  double inv_extra = 1.0 / pf;
  double inv_interp = 1.0 / (40.0 * pf);
  double twopi = 6.283185307179586476925286766559;
  double lnb2 = 2.0 * log(10000.0);
  double lowd = floor(64.0 * log(4096.0 / (32.0 * twopi)) / lnb2);
  if (lowd < 0.0) lowd = 0.0;
  double highd = ceil(64.0 * log(4096.0 / twopi) / lnb2);
  if (highd > 63.0) highd = 63.0;
  double denom = highd - lowd;
  if (denom < 0.001) denom = 0.001;
  double ramp = ((double)j - lowd) / denom;
  ramp = ramp < 0.0 ? 0.0 : (ramp > 1.0 ? 1.0 : ramp);
  float invf = (float)(inv_interp * ramp + inv_extra * (1.0 - ramp));
  float fr = (float)s * invf;
  cs[idx] = cosf(fr);
  sn[idx] = sinf(fr);
}

// ---------------- bf16 GEMM body: dbuf LDS + counted vmcnt + swz ----------
// C[*,N] = A[*,Kstride restricted to Klen] * BT[N,Kstride]^T
// LDS layout linear [row][32]; global source granule-swizzled so that the
// fragment ds_read_b128 is 2-way max (both-sides swizzle, G21).
template <typename OutT>
DEV void gemm_body(u16* Al, u16* Bl, const u16* __restrict__ A,
                   const u16* __restrict__ BT, OutT* __restrict__ C,
                   int N, int Kstride, int Klen, int mbase, int nbase) {
  const int tid = threadIdx.x;
  const int lane = tid & 63, wave = tid >> 6;
  const int wr = wave >> 1, wc = wave & 1;
  const int lr = lane & 15, lk = lane >> 4;
  const int srow = wave * 32 + (lane >> 2);
  const int skoff = (((lane & 3) ^ ((lane >> 3) & 3))) * 8;  // source swizzle
  const int swlk8 = (lk ^ ((lr >> 1) & 3)) * 8;              // read swizzle
  const u16* aptr = A + (size_t)(mbase + srow) * Kstride + skoff;
  const u16* bptr = BT + (size_t)(nbase + srow) * Kstride + skoff;
  u16* alw = Al + wave * (32 * 32);
  u16* blw = Bl + wave * (32 * 32);

  auto STAGE = [&](int b, int kk) {
    gload_lds16(aptr + kk, alw + b * 4096);
    gload_lds16(aptr + (size_t)16 * Kstride + kk, alw + b * 4096 + 16 * 32);
    gload_lds16(bptr + kk, blw + b * 4096);
    gload_lds16(bptr + (size_t)16 * Kstride + kk, blw + b * 4096 + 16 * 32);
  };

  f32x4 acc[4][4];
#pragma unroll
  for (int mf = 0; mf < 4; ++mf)
#pragma unroll
    for (int nf = 0; nf < 4; ++nf) acc[mf][nf] = {0.f, 0.f, 0.f, 0.f};

  const int nt = Klen >> 5;
  STAGE(0, 0);
  STAGE(1, 32);
  for (int t = 0; t < nt; ++t) {
    const int cur = t & 1;
    if (t + 1 < nt)
      asm volatile("s_waitcnt vmcnt(4)" ::: "memory");  // cur tile done, next in flight
    else
      asm volatile("s_waitcnt vmcnt(0)" ::: "memory");
    __builtin_amdgcn_s_barrier();
    const u16* Ac = Al + cur * 4096;
    const u16* Bc = Bl + cur * 4096;
    bf16x8 af[4], bfr[4];
#pragma unroll
    for (int mf = 0; mf < 4; ++mf)
      af[mf] = *reinterpret_cast<const bf16x8*>(Ac + (wr * 64 + mf * 16 + lr) * 32 + swlk8);
#pragma unroll
    for (int nf = 0; nf < 4; ++nf)
      bfr[nf] = *reinterpret_cast<const bf16x8*>(Bc + (wc * 64 + nf * 16 + lr) * 32 + swlk8);
#pragma unroll
    for (int mf = 0; mf < 4; ++mf)
#pragma unroll
      for (int nf = 0; nf < 4; ++nf)
        acc[mf][nf] = __builtin_amdgcn_mfma_f32_16x16x32_bf16(af[mf], bfr[nf], acc[mf][nf], 0, 0, 0);
    __builtin_amdgcn_s_barrier();  // everyone done reading buf[cur]
    if (t + 2 < nt) STAGE(cur, (t + 2) * 32);
  }

#pragma unroll
  for (int mf = 0; mf < 4; ++mf)
#pragma unroll
    for (int nf = 0; nf < 4; ++nf) {
      int col = nbase + wc * 64 + nf * 16 + lr;
      if (col < N) {
#pragma unroll
        for (int r = 0; r < 4; ++r) {
          int row = mbase + wr * 64 + mf * 16 + lk * 4 + r;
          store_out(&C[(size_t)row * N + col], acc[mf][nf][r]);
        }
      }
    }
}

template <typename OutT>
__global__ __launch_bounds__(256) void k_gemm(const u16* __restrict__ A,
                                              const u16* __restrict__ BT,
                                              OutT* __restrict__ C, int N, int K) {
  __shared__ u16 Al[2 * 128 * 32];
  __shared__ u16 Bl[2 * 128 * 32];
  gemm_body(Al, Bl, A, BT, C, N, K, K, blockIdx.y * 128, blockIdx.x * 128);
}

// two independent GEMMs in one launch (fills the machine)
template <typename OutT>
__global__ __launch_bounds__(256) void k_gemm2(const u16* __restrict__ A0, const u16* __restrict__ B0,
                                               OutT* __restrict__ C0, int N0, int K0, int nbx0,
                                               const u16* __restrict__ A1, const u16* __restrict__ B1,
                                               OutT* __restrict__ C1, int N1, int K1) {
  __shared__ u16 Al[2 * 128 * 32];
  __shared__ u16 Bl[2 * 128 * 32];
  int bx = blockIdx.x;
  if (bx < nbx0)
    gemm_body(Al, Bl, A0, B0, C0, N0, K0, K0, blockIdx.y * 128, bx * 128);
  else
    gemm_body(Al, Bl, A1, B1, C1, N1, K1, K1, blockIdx.y * 128, (bx - nbx0) * 128);
}

// down-proj, split-K=2: both GEMMs, both splits, one launch (544 blocks)
__global__ __launch_bounds__(256) void k_gemm_dp(const u16* __restrict__ A,
                                                 const u16* __restrict__ Bq,
                                                 const u16* __restrict__ Bkv,
                                                 float* __restrict__ q0, float* __restrict__ q1,
                                                 float* __restrict__ l0, float* __restrict__ l1) {
  __shared__ u16 Al[2 * 128 * 32];
  __shared__ u16 Bl[2 * 128 * 32];
  constexpr int KH = HIDDEN / 2;  // 2560
  int bx = blockIdx.x;
  int split = bx >= 17;
  int j = bx - split * 17;
  const u16* As = A + split * KH;
  if (j < 12) {
    gemm_body(Al, Bl, As, Bq + split * KH, split ? q1 : q0, QLORA, HIDDEN, KH,
              blockIdx.y * 128, j * 128);
  } else {
    gemm_body(Al, Bl, As, Bkv + split * KH, split ? l1 : l0, KVA_N, HIDDEN, KH,
              blockIdx.y * 128, (j - 12) * 128);
  }
}

// ---------------- RMSNorm over (x0+x1) fp32 -> bf16 ----------------
__global__ __launch_bounds__(256) void k_rmsnorm2(const float* __restrict__ x0,
                                                  const float* __restrict__ x1,
                                                  const float* __restrict__ w,
                                                  u16* __restrict__ y, int ncols, int instride) {
  int row = blockIdx.x, tid = threadIdx.x;
  const float* xr0 = x0 + (size_t)row * instride;
  const float* xr1 = x1 + (size_t)row * instride;
  float ss = 0.f;
  for (int i = tid * 4; i < ncols; i += 1024) {
    f32x4 a = *reinterpret_cast<const f32x4*>(xr0 + i);
    f32x4 b = *reinterpret_cast<const f32x4*>(xr1 + i);
    f32x4 v = a + b;
    ss += v[0] * v[0] + v[1] * v[1] + v[2] * v[2] + v[3] * v[3];
  }
  for (int off = 32; off > 0; off >>= 1) ss += __shfl_down(ss, off);
  __shared__ float red[4];
  if ((tid & 63) == 0) red[tid >> 6] = ss;
  __syncthreads();
  ss = red[0] + red[1] + red[2] + red[3];
  float sc = rsqrtf(ss / (float)ncols + 1e-6f);
  u16* yr = y + (size_t)row * ncols;
  for (int i = tid * 4; i < ncols; i += 1024) {
    f32x4 a = *reinterpret_cast<const f32x4*>(xr0 + i);
    f32x4 b = *reinterpret_cast<const f32x4*>(xr1 + i);
    f32x4 v = a + b;
    u16x4 o;
    o[0] = f2b(v[0] * sc * w[i]);
    o[1] = f2b(v[1] * sc * w[i + 1]);
    o[2] = f2b(v[2] * sc * w[i + 2]);
    o[3] = f2b(v[3] * sc * w[i + 3]);
    *reinterpret_cast<u16x4*>(yr + i) = o;
  }
}

// ---------------- build qf [H][S][192], kf [H][S][192] with RoPE ----------------
__global__ __launch_bounds__(256) void k_build_qkf(const u16* __restrict__ qn,
                                                   const u16* __restrict__ kv,
                                                   const float* __restrict__ lat0,
                                                   const float* __restrict__ lat1,
                                                   const float* __restrict__ cs,
                                                   const float* __restrict__ sn,
                                                   u16* __restrict__ qf, u16* __restrict__ kf) {
  int s = blockIdx.x, tid = threadIdx.x;
  for (int idx = tid; idx < H * NOPE; idx += 256) {
    int h = idx >> 7, dd = idx & 127;
    qf[((size_t)h * S + s) * QKD + dd] = qn[(size_t)s * (H * QKD) + h * QKD + dd];
    kf[((size_t)h * S + s) * QKD + dd] = kv[(size_t)s * (H * 256) + h * 256 + dd];
  }
  for (int idx = tid; idx < H * 32; idx += 256) {
    int h = idx >> 5, j = idx & 31;
    float c = cs[s * 32 + j], si = sn[s * 32 + j];
    float x1 = b2f(qn[(size_t)s * (H * QKD) + h * QKD + NOPE + 2 * j]);
    float x2 = b2f(qn[(size_t)s * (H * QKD) + h * QKD + NOPE + 2 * j + 1]);
    qf[((size_t)h * S + s) * QKD + NOPE + 2 * j] = f2b(x1 * c - x2 * si);
    qf[((size_t)h * S + s) * QKD + NOPE + 2 * j + 1] = f2b(x2 * c + x1 * si);
    float k1 = lat0[(size_t)s * KVA_N + KVLORA + 2 * j] + lat1[(size_t)s * KVA_N + KVLORA + 2 * j];
    float k2 = lat0[(size_t)s * KVA_N + KVLORA + 2 * j + 1] + lat1[(size_t)s * KVA_N + KVLORA + 2 * j + 1];
    kf[((size_t)h * S + s) * QKD + NOPE + 2 * j] = f2b(k1 * c - k2 * si);
    kf[((size_t)h * S + s) * QKD + NOPE + 2 * j + 1] = f2b(k2 * c + k1 * si);
  }
}

// ---------------- build vt [H][128][S] (transposed V) ----------------
__global__ void k_build_vt(const u16* __restrict__ kv, u16* __restrict__ vt) {
  __shared__ u16 t[32][33];
  int s0 = blockIdx.x * 32, d0 = blockIdx.y * 32, h = blockIdx.z;
  int tx = threadIdx.x, ty = threadIdx.y;
  for (int r = ty; r < 32; r += 8)
    t[r][tx] = kv[(size_t)(s0 + r) * (H * 256) + h * 256 + NOPE + d0 + tx];
  __syncthreads();
  for (int r = ty; r < 32; r += 8)
    vt[((size_t)h * VD + d0 + r) * S + s0 + tx] = t[tx][r];
}

// ---------------- flash attention (causal), per head ----------------
__global__ __launch_bounds__(256) void k_attn(const u16* __restrict__ qf,
                                              const u16* __restrict__ kf,
                                              const u16* __restrict__ vt,
                                              u16* __restrict__ attn) {
  const int bidx = blockIdx.x;
  const int j = bidx & 31;
  const int h = bidx >> 5;
  const int qt = (h < 8) ? j : 31 - j;
  const int qbase = qt * 64;
  const int tid = threadIdx.x, wave = tid >> 6, lane = tid & 63;
  const int lr = lane & 15, lk = lane >> 4;
  __shared__ u16 Kl[64][192];
  __shared__ u16 Vl[128][64];
  __shared__ u16 Pl[4][16][64];

  int krow_[6], kofs_[6], vrow_[4], vofs_[4];
#pragma unroll
  for (int i = 0; i < 6; ++i) { int c = tid + i * 256; krow_[i] = c / 24; kofs_[i] = (c % 24) * 8; }
#pragma unroll
  for (int i = 0; i < 4; ++i) { int c = tid + i * 256; vrow_[i] = c >> 3; vofs_[i] = (c & 7) * 8; }
  const u16* kfh = kf + (size_t)h * S * QKD;
  const u16* vth = vt + (size_t)h * VD * S;

  bf16x8 qfrag[6];
  const u16* qrow = qf + ((size_t)h * S + qbase + wave * 16 + lr) * QKD;
#pragma unroll
  for (int d = 0; d < 6; ++d)
    qfrag[d] = *reinterpret_cast<const bf16x8*>(qrow + d * 32 + lk * 8);

  u16x8 kreg[6], vreg[4];
#pragma unroll
  for (int i = 0; i < 6; ++i)
    kreg[i] = *reinterpret_cast<const u16x8*>(kfh + (size_t)krow_[i] * QKD + kofs_[i]);
#pragma unroll
  for (int i = 0; i < 4; ++i)
    vreg[i] = *reinterpret_cast<const u16x8*>(vth + (size_t)vrow_[i] * S + vofs_[i]);

  f32x4 o[8];
#pragma unroll
  for (int f = 0; f < 8; ++f) o[f] = {0.f, 0.f, 0.f, 0.f};
  float m_[4] = {-__builtin_inff(), -__builtin_inff(), -__builtin_inff(), -__builtin_inff()};
  float l_[4] = {0.f, 0.f, 0.f, 0.f};

  const int ktiles = qt + 1;
  for (int kt = 0; kt < ktiles; ++kt) {
    const int kbase = kt * 64;
    __builtin_amdgcn_s_barrier();
#pragma unroll
    for (int i = 0; i < 6; ++i)
      *reinterpret_cast<u16x8*>(&Kl[krow_[i]][SWZ(krow_[i], kofs_[i])]) = kreg[i];
#pragma unroll
    for (int i = 0; i < 4; ++i)
      *reinterpret_cast<u16x8*>(&Vl[vrow_[i]][SWZ(vrow_[i], vofs_[i])]) = vreg[i];
    if (kt + 1 < ktiles) {
      const int nb = kbase + 64;
#pragma unroll
      for (int i = 0; i < 6; ++i)
        kreg[i] = *reinterpret_cast<const u16x8*>(kfh + (size_t)(nb + krow_[i]) * QKD + kofs_[i]);
#pragma unroll
      for (int i = 0; i < 4; ++i)
        vreg[i] = *reinterpret_cast<const u16x8*>(vth + (size_t)vrow_[i] * S + nb + vofs_[i]);
    }
    asm volatile("s_waitcnt lgkmcnt(0)" ::: "memory");
    __builtin_amdgcn_s_barrier();

    f32x4 sacc[4];
#pragma unroll
    for (int nf = 0; nf < 4; ++nf) sacc[nf] = {0.f, 0.f, 0.f, 0.f};
    __builtin_amdgcn_s_setprio(1);
#pragma unroll
    for (int nf = 0; nf < 4; ++nf)
#pragma unroll
      for (int dk = 0; dk < 6; ++dk) {
        int krow = nf * 16 + lr;
        bf16x8 b = *reinterpret_cast<const bf16x8*>(&Kl[krow][SWZ(krow, dk * 32 + lk * 8)]);
        sacc[nf] = __builtin_amdgcn_mfma_f32_16x16x32_bf16(qfrag[dk], b, sacc[nf], 0, 0, 0);
      }
    __builtin_amdgcn_s_setprio(0);

    float sv[4][4];
    float rowmax[4] = {-__builtin_inff(), -__builtin_inff(), -__builtin_inff(), -__builtin_inff()};
#pragma unroll
    for (int nf = 0; nf < 4; ++nf) {
      int kcol = kbase + nf * 16 + lr;
#pragma unroll
      for (int r = 0; r < 4; ++r) {
        float v = sacc[nf][r] * SCALING;
        int qrow_g = qbase + wave * 16 + lk * 4 + r;
        if (kcol > qrow_g) v = -__builtin_inff();
        sv[nf][r] = v;
        rowmax[r] = fmaxf(rowmax[r], v);
      }
    }
#pragma unroll
    for (int r = 0; r < 4; ++r) {
#pragma unroll
      for (int off = 1; off < 16; off <<= 1)
        rowmax[r] = fmaxf(rowmax[r], __shfl_xor(rowmax[r], off));
    }
    float alpha[4], rowsum[4] = {0.f, 0.f, 0.f, 0.f};
#pragma unroll
    for (int r = 0; r < 4; ++r) {
      float mn = fmaxf(m_[r], rowmax[r]);
      alpha[r] = __expf(m_[r] - mn);
      m_[r] = mn;
    }
#pragma unroll
    for (int nf = 0; nf < 4; ++nf)
#pragma unroll
      for (int r = 0; r < 4; ++r) {
        float p = __expf(sv[nf][r] - m_[r]);
        sv[nf][r] = p;
        rowsum[r] += p;
      }
#pragma unroll
    for (int r = 0; r < 4; ++r) {
#pragma unroll
      for (int off = 1; off < 16; off <<= 1) rowsum[r] += __shfl_xor(rowsum[r], off);
      l_[r] = l_[r] * alpha[r] + rowsum[r];
    }
#pragma unroll
    for (int nf = 0; nf < 4; ++nf)
#pragma unroll
      for (int r = 0; r < 4; ++r) {
        int prow = lk * 4 + r;
        Pl[wave][prow][SWZ(prow, nf * 16 + lr)] = f2b(sv[nf][r]);
      }
#pragma unroll
    for (int f = 0; f < 8; ++f)
#pragma unroll
      for (int r = 0; r < 4; ++r) o[f][r] *= alpha[r];

    __builtin_amdgcn_s_setprio(1);
#pragma unroll
    for (int kk = 0; kk < 2; ++kk) {
      bf16x8 pa = *reinterpret_cast<const bf16x8*>(&Pl[wave][lr][SWZ(lr, kk * 32 + lk * 8)]);
#pragma unroll
      for (int f = 0; f < 8; ++f) {
        int vrow = f * 16 + lr;
        bf16x8 b = *reinterpret_cast<const bf16x8*>(&Vl[vrow][SWZ(vrow, kk * 32 + lk * 8)]);
        o[f] = __builtin_amdgcn_mfma_f32_16x16x32_bf16(pa, b, o[f], 0, 0, 0);
      }
    }
    __builtin_amdgcn_s_setprio(0);
  }

#pragma unroll
  for (int f = 0; f < 8; ++f)
#pragma unroll
    for (int r = 0; r < 4; ++r) {
      int row = qbase + wave * 16 + lk * 4 + r;
      float val = o[f][r] / l_[r];
      attn[(size_t)row * (H * VD) + h * VD + f * 16 + lr] = f2b(val);
    }
}

// ---------------- host launch ----------------
extern "C" void kernel_launch(void* const* d_in, const int* in_sizes, int n_in,
                              void* d_out, int out_size, void* d_ws, size_t ws_size,
                              hipStream_t stream) {
  (void)in_sizes; (void)n_in; (void)out_size; (void)ws_size;
  const float* hidden    = (const float*)d_in[1];
  const float* w_q_a     = (const float*)d_in[2];
  const float* q_a_ln_w  = (const float*)d_in[3];
  const float* w_q_b     = (const float*)d_in[4];
  const float* w_kv_a    = (const float*)d_in[5];
  const float* kv_a_ln_w = (const float*)d_in[6];
  const float* w_kv_b    = (const float*)d_in[7];
  const float* w_o       = (const float*)d_in[8];
  float* out = (float*)d_out;

  char* ws = (char*)d_ws;
  size_t off = 0;
  auto alloc = [&](size_t bytes) {
    size_t o = off;
    off += (bytes + 255) & ~(size_t)255;
    return o;
  };
  constexpr int KVA_PAD = 640;  // 576 padded to multiple of 128 (unguarded DMA)
  size_t o_hs    = alloc((size_t)S * HIDDEN * 2);        // hs bf16; later reused as qf
  size_t o_btqa  = alloc((size_t)QLORA * HIDDEN * 2);    // later reused (with o_btkva) as bt_o
  size_t o_btkva = alloc((size_t)KVA_PAD * HIDDEN * 2);
  size_t o_btqb  = alloc((size_t)(H * QKD) * QLORA * 2);
  size_t o_btkvb = alloc((size_t)(H * 256) * KVLORA * 2);
  size_t o_qlat0 = alloc((size_t)S * QLORA * 4);         // later reused as attn
  size_t o_qlat1 = alloc((size_t)S * QLORA * 4);
  size_t o_lat0  = alloc((size_t)S * KVA_N * 4);
  size_t o_lat1  = alloc((size_t)S * KVA_N * 4);
  size_t o_qln   = alloc((size_t)S * QLORA * 2);
  size_t o_kvln  = alloc((size_t)S * KVLORA * 2);
  size_t o_qn    = alloc((size_t)S * (H * QKD) * 2);
  size_t o_kv    = alloc((size_t)S * (H * 256) * 2);
  size_t o_kf    = alloc((size_t)H * S * QKD * 2);
  size_t o_vt    = alloc((size_t)H * VD * S * 2);
  size_t o_cs    = alloc((size_t)S * 32 * 4);
  size_t o_sn    = alloc((size_t)S * 32 * 4);

  u16* hs_bf  = (u16*)(ws + o_hs);
  u16* bt_qa  = (u16*)(ws + o_btqa);
  u16* bt_kva = (u16*)(ws + o_btkva);
  u16* bt_qb  = (u16*)(ws + o_btqb);
  u16* bt_kvb = (u16*)(ws + o_btkvb);
  float* q_lat0 = (float*)(ws + o_qlat0);
  float* q_lat1 = (float*)(ws + o_qlat1);
  float* lat0   = (float*)(ws + o_lat0);
  float* lat1   = (float*)(ws + o_lat1);
  u16* q_ln  = (u16*)(ws + o_qln);
  u16* kv_ln = (u16*)(ws + o_kvln);
  u16* qn    = (u16*)(ws + o_qn);
  u16* kvb   = (u16*)(ws + o_kv);
  u16* kf    = (u16*)(ws + o_kf);
  u16* vt    = (u16*)(ws + o_vt);
  float* cs = (float*)(ws + o_cs);
  float* sn = (float*)(ws + o_sn);
  // aliases (lifetimes verified: source buffers dead before alias written)
  u16* qf   = (u16*)(ws + o_hs);
  u16* bt_o = (u16*)(ws + o_btqa);
  u16* attn = (u16*)(ws + o_qlat0);

  dim3 t256(256), t32x8(32, 8);

  // prep
  k_convert<<<(S * HIDDEN / 4 + 255) / 256, t256, 0, stream>>>(hidden, hs_bf, S * HIDDEN);
  k_transpose<<<dim3(QLORA / 32, HIDDEN / 32), t32x8, 0, stream>>>(w_q_a, bt_qa, HIDDEN, QLORA);
  k_transpose<<<dim3(KVA_N / 32, HIDDEN / 32), t32x8, 0, stream>>>(w_kv_a, bt_kva, HIDDEN, KVA_N);
  k_transpose<<<dim3(H * QKD / 32, QLORA / 32), t32x8, 0, stream>>>(w_q_b, bt_qb, QLORA, H * QKD);
  k_transpose<<<dim3(H * 256 / 32, KVLORA / 32), t32x8, 0, stream>>>(w_kv_b, bt_kvb, KVLORA, H * 256);
  k_rope_tables<<<(S * 32 + 255) / 256, t256, 0, stream>>>(cs, sn);

  // down-projections: split-K=2, 34x16 = 544 blocks (~2.1/CU)
  k_gemm_dp<<<dim3(34, S / 128), t256, 0, stream>>>(hs_bf, bt_qa, bt_kva,
                                                    q_lat0, q_lat1, lat0, lat1);

  // norms (fused split-K reduce)
  k_rmsnorm2<<<S, t256, 0, stream>>>(q_lat0, q_lat1, q_a_ln_w, q_ln, QLORA, QLORA);
  k_rmsnorm2<<<S, t256, 0, stream>>>(lat0, lat1, kv_a_ln_w, kv_ln, KVLORA, KVA_N);

  // up-projections: G3 (N=3072,K=1536) + G4 (N=4096,K=512) grouped, 896 blocks
  k_gemm2<u16><<<dim3((H * QKD) / 128 + (H * 256) / 128, S / 128), t256, 0, stream>>>(
      q_ln, bt_qb, qn, H * QKD, QLORA, (H * QKD) / 128,
      kv_ln, bt_kvb, kvb, H * 256, KVLORA);

  // rearrange + RoPE
  k_build_qkf<<<S, t256, 0, stream>>>(qn, kvb, lat0, lat1, cs, sn, qf, kf);
  k_build_vt<<<dim3(S / 32, VD / 32, H), t32x8, 0, stream>>>(kvb, vt);

  // transpose w_o (into region freed after down-projections)
  k_transpose<<<dim3(HIDDEN / 32, (H * VD) / 32), t32x8, 0, stream>>>(w_o, bt_o, H * VD, HIDDEN);

  // attention (flat 512-block grid, work-balanced qt mapping)
  k_attn<<<dim3(512), t256, 0, stream>>>(qf, kf, vt, attn);

  // output projection
  k_gemm<float><<<dim3(HIDDEN / 128, S / 128), t256, 0, stream>>>(attn, bt_o, out, HIDDEN, H * VD);
}